// Round 3
// baseline (1466.342 us; speedup 1.0000x reference)
//
#include <hip/hip_runtime.h>
#include <math.h>

#define N_PIX 4096
#define CCH 64

typedef __attribute__((ext_vector_type(8))) short short8;
typedef __attribute__((ext_vector_type(4))) float f32x4;

// LDS tiles are [rows][68] floats; XOR-swizzle the 4-float granule by (row>>2)&7
// so that 4-row-strided b128 reads spread across bank groups (else 8-way conflict).
__device__ __forceinline__ int swz(int row, int col) {
  return row * 68 + (col ^ (((row >> 2) & 7) << 2));
}

__device__ __forceinline__ float fget(const float4& v, int j) {
  return ((const float*)&v)[j];
}

__device__ __forceinline__ unsigned short f2bf(float f) {
  unsigned u = __float_as_uint(f);
  unsigned r = (u + 0x7fff + ((u >> 16) & 1)) >> 16;
  return (unsigned short)r;
}
__device__ __forceinline__ float bf2f(unsigned short h) {
  return __uint_as_float((unsigned)h << 16);
}

// ---------------- weight prep: fold conv weights into wq|wk|wv ----------------
// Weff[t*64+i][e] = sum_o w5[o,i,t]*Wcat[128+o][e] + (inner) w3[o,i,t3]*Wcat[64+o][e]
//                 + (center) w1[o,i]*Wcat[o][e],  Wcat = [wq | wk | wv] cols 0..191.
// Written directly in MFMA B-fragment order: frag f=(t*12+q)*2+s holds
// B[k=t*64+s*32+(lane>>4)*8+j][e=q*16+(lane&15)] at Bf[f*512 + lane*8 + j].
__global__ __launch_bounds__(192) void prep_kernel(
    const float* __restrict__ w1, const float* __restrict__ w3,
    const float* __restrict__ w5, const float* __restrict__ wq,
    const float* __restrict__ wk, const float* __restrict__ wv,
    unsigned short* __restrict__ Bfh, unsigned short* __restrict__ Bfl) {
  const int t = blockIdx.x;
  const int ky = t / 5, kx = t % 5;
  const int e = threadIdx.x;  // 0..191
  const int em = e & 63, which = e >> 6;
  const float* Wsel = which == 0 ? wq : (which == 1 ? wk : wv);
  const bool in3 = (ky >= 1 && ky <= 3 && kx >= 1 && kx <= 3);
  const bool c1 = (t == 12);
  const int t3 = (ky - 1) * 3 + (kx - 1);
  float acc[64];
#pragma unroll
  for (int i = 0; i < 64; ++i) acc[i] = 0.f;
  for (int o = 0; o < 64; ++o) {
    const float wc5 = Wsel[(128 + o) * 64 + em];
    const float wc3 = in3 ? Wsel[(64 + o) * 64 + em] : 0.f;
    const float wc1 = c1 ? Wsel[o * 64 + em] : 0.f;
    const float* w5p = w5 + (size_t)(o * 64) * 25 + t;
    const float* w3p = w3 + (size_t)(o * 64) * 9 + t3;
    const float* w1p = w1 + o * 64;
#pragma unroll
    for (int i = 0; i < 64; ++i) {
      float s = w5p[(size_t)i * 25] * wc5;
      if (in3) s += w3p[(size_t)i * 9] * wc3;
      if (c1) s += w1p[i] * wc1;
      acc[i] += s;
    }
  }
  const int q = e >> 4, lr = e & 15;
#pragma unroll
  for (int i = 0; i < 64; ++i) {
    const int s = i >> 5, lg = (i >> 3) & 3, j = i & 7;
    const int lane = lg * 16 + lr;
    const size_t off = ((size_t)(t * 12 + q) * 2 + s) * 512 + lane * 8 + j;
    const unsigned short h = f2bf(acc[i]);
    Bfh[off] = h;
    Bfl[off] = f2bf(acc[i] - bf2f(h));
  }
}

// effective bias: beff[e] = bcat[e] + sum_row bconv[row] * Wcat[row][e]
__global__ __launch_bounds__(192) void beff_kernel(
    const float* __restrict__ b1, const float* __restrict__ b3,
    const float* __restrict__ b5, const float* __restrict__ bq,
    const float* __restrict__ bk, const float* __restrict__ bv,
    const float* __restrict__ wq, const float* __restrict__ wk,
    const float* __restrict__ wv, float* __restrict__ beff) {
  const int e = threadIdx.x;
  const int em = e & 63, which = e >> 6;
  const float* Wsel = which == 0 ? wq : (which == 1 ? wk : wv);
  const float* bsel = which == 0 ? bq : (which == 1 ? bk : bv);
  float s = bsel[em];
  for (int row = 0; row < 192; ++row) {
    const float bc = row < 64 ? b1[row] : (row < 128 ? b3[row - 64] : b5[row - 128]);
    s += bc * Wsel[row * 64 + em];
  }
  beff[e] = s;
}

// ---------------- fused im2col GEMM: x -> Q(hi/lo), K(hi/lo), V ----------------
// Block: 64 pixels (8x8 spatial) x 192 outputs. 8 waves: wave = (half, pg);
// wave handles pixel-group pg (16 pixels), output quadrants half*6..half*6+5.
__global__ __launch_bounds__(512) void fused_qkv_kernel(
    const float* __restrict__ x, const unsigned short* __restrict__ Bfh,
    const unsigned short* __restrict__ Bfl, const float* __restrict__ beff,
    unsigned short* __restrict__ Qhi, unsigned short* __restrict__ Qlo,
    unsigned short* __restrict__ Khi, unsigned short* __restrict__ Klo,
    float* __restrict__ Vm) {
  __shared__ unsigned short Lh[144 * 64];
  __shared__ unsigned short Ll[144 * 64];
  const int b = blockIdx.y;
  const int sb = blockIdx.x;
  const int y0 = (sb >> 3) * 8, x0 = (sb & 7) * 8;
  const int tid = threadIdx.x;
  const int l = tid & 63, lr = l & 15, lg = l >> 4;
  const int pg = (tid >> 6) & 3, half6 = (tid >> 8) * 6;
  const float* xb = x + (size_t)b * CCH * N_PIX;
  // stage 12x12x64 patch as bf16 hi/lo, XOR-swizzled on the 8-ch granule
  for (int it = 0; it < 18; ++it) {
    const int idx = it * 512 + tid;
    const int c = idx / 144;
    const int pr = idx - c * 144;
    const int py = pr / 12, px = pr - py * 12;
    const int gy = y0 - 2 + py, gx = x0 - 2 + px;
    float v = 0.f;
    if (gy >= 0 && gy < 64 && gx >= 0 && gx < 64) v = xb[c * N_PIX + gy * 64 + gx];
    const unsigned short h = f2bf(v);
    const int a = pr * 64 + (c ^ ((pr & 7) << 3));
    Lh[a] = h;
    Ll[a] = f2bf(v - bf2f(h));
  }
  __syncthreads();
  const int p = pg * 16 + lr;  // this lane's A-row pixel
  const int prp = (p >> 3) * 12 + (p & 7);
  f32x4 acc[6];
#pragma unroll
  for (int q6 = 0; q6 < 6; ++q6) acc[q6] = (f32x4){0.f, 0.f, 0.f, 0.f};
  for (int ky = 0; ky < 5; ++ky) {
    for (int kx = 0; kx < 5; ++kx) {
      const int t = ky * 5 + kx;
      const int prt = prp + ky * 12 + kx;
      const int rb = prt * 64, sw = (prt & 7) << 3;
      const short8 ah0 = *(const short8*)&Lh[rb + ((lg << 3) ^ sw)];
      const short8 ah1 = *(const short8*)&Lh[rb + ((32 + (lg << 3)) ^ sw)];
      const short8 al0 = *(const short8*)&Ll[rb + ((lg << 3) ^ sw)];
      const short8 al1 = *(const short8*)&Ll[rb + ((32 + (lg << 3)) ^ sw)];
#pragma unroll
      for (int q6 = 0; q6 < 6; ++q6) {
        const size_t f = ((size_t)(t * 12 + half6 + q6)) * 2;
        const short8 bh0 = *(const short8*)&Bfh[f * 512 + l * 8];
        const short8 bh1 = *(const short8*)&Bfh[(f + 1) * 512 + l * 8];
        const short8 bl0 = *(const short8*)&Bfl[f * 512 + l * 8];
        const short8 bl1 = *(const short8*)&Bfl[(f + 1) * 512 + l * 8];
        acc[q6] = __builtin_amdgcn_mfma_f32_16x16x32_bf16(ah0, bh0, acc[q6], 0, 0, 0);
        acc[q6] = __builtin_amdgcn_mfma_f32_16x16x32_bf16(ah1, bh1, acc[q6], 0, 0, 0);
        acc[q6] = __builtin_amdgcn_mfma_f32_16x16x32_bf16(al0, bh0, acc[q6], 0, 0, 0);
        acc[q6] = __builtin_amdgcn_mfma_f32_16x16x32_bf16(al1, bh1, acc[q6], 0, 0, 0);
        acc[q6] = __builtin_amdgcn_mfma_f32_16x16x32_bf16(ah0, bl0, acc[q6], 0, 0, 0);
        acc[q6] = __builtin_amdgcn_mfma_f32_16x16x32_bf16(ah1, bl1, acc[q6], 0, 0, 0);
      }
    }
  }
  // epilogue: D col = l&15 -> e, row = lg*4+r -> pixel
  const size_t base = (size_t)b * N_PIX;
#pragma unroll
  for (int q6 = 0; q6 < 6; ++q6) {
    const int e = (half6 + q6) * 16 + lr;
    const int which = e >> 6, em = e & 63;
    const float be = beff[e];
#pragma unroll
    for (int r = 0; r < 4; ++r) {
      const int pp = pg * 16 + lg * 4 + r;
      const int n = (y0 + (pp >> 3)) * 64 + x0 + (pp & 7);
      const float val = acc[q6][r] + be;
      const size_t off = (base + n) * 64 + em;
      if (which == 2) {
        Vm[off] = val;
      } else {
        const unsigned short h = f2bf(val);
        const unsigned short lo = f2bf(val - bf2f(h));
        if (which == 0) {
          Qhi[off] = h;
          Qlo[off] = lo;
        } else {
          Khi[off] = h;
          Klo[off] = lo;
        }
      }
    }
  }
}

// ---------------- sweep 1: partial row sums of exp(z), MFMA split-bf16 ----------------
__global__ __launch_bounds__(256) void qk_s_kernel(
    const unsigned short* __restrict__ Qhi, const unsigned short* __restrict__ Qlo,
    const unsigned short* __restrict__ Khi, const unsigned short* __restrict__ Klo,
    float* __restrict__ s_part) {
  __shared__ float red[4][64];
  const int b = blockIdx.z, kc = blockIdx.y, q0 = blockIdx.x * 64;
  const int tid = threadIdx.x, w = tid >> 6, l = tid & 63;
  const int lr = l & 15, lg = l >> 4;
  const size_t base = (size_t)b * N_PIX;
  short8 qh[4][2], ql[4][2];
#pragma unroll
  for (int qs = 0; qs < 4; ++qs) {
    const size_t qoff = (base + q0 + qs * 16 + lr) * 64 + lg * 8;
    qh[qs][0] = *(const short8*)(Qhi + qoff);
    qh[qs][1] = *(const short8*)(Qhi + qoff + 32);
    ql[qs][0] = *(const short8*)(Qlo + qoff);
    ql[qs][1] = *(const short8*)(Qlo + qoff + 32);
  }
  float racc[4][4];
#pragma unroll
  for (int qs = 0; qs < 4; ++qs)
#pragma unroll
    for (int r = 0; r < 4; ++r) racc[qs][r] = 0.f;
  for (int kt = w; kt < 8; kt += 4) {
    const int kb = kc * 512 + kt * 64;
#pragma unroll
    for (int ct = 0; ct < 4; ++ct) {
      const size_t koff = (base + kb + ct * 16 + lr) * 64 + lg * 8;
      const short8 kh0 = *(const short8*)(Khi + koff);
      const short8 kh1 = *(const short8*)(Khi + koff + 32);
      const short8 kl0 = *(const short8*)(Klo + koff);
      const short8 kl1 = *(const short8*)(Klo + koff + 32);
#pragma unroll
      for (int qs = 0; qs < 4; ++qs) {
        f32x4 acc = {0.f, 0.f, 0.f, 0.f};
        acc = __builtin_amdgcn_mfma_f32_16x16x32_bf16(qh[qs][0], kh0, acc, 0, 0, 0);
        acc = __builtin_amdgcn_mfma_f32_16x16x32_bf16(qh[qs][1], kh1, acc, 0, 0, 0);
        acc = __builtin_amdgcn_mfma_f32_16x16x32_bf16(ql[qs][0], kh0, acc, 0, 0, 0);
        acc = __builtin_amdgcn_mfma_f32_16x16x32_bf16(ql[qs][1], kh1, acc, 0, 0, 0);
        acc = __builtin_amdgcn_mfma_f32_16x16x32_bf16(qh[qs][0], kl0, acc, 0, 0, 0);
        acc = __builtin_amdgcn_mfma_f32_16x16x32_bf16(qh[qs][1], kl1, acc, 0, 0, 0);
#pragma unroll
        for (int r = 0; r < 4; ++r) racc[qs][r] += __expf(acc[r] * 0.125f);
      }
    }
  }
#pragma unroll
  for (int qs = 0; qs < 4; ++qs)
#pragma unroll
    for (int r = 0; r < 4; ++r)
#pragma unroll
      for (int m = 1; m < 16; m <<= 1) racc[qs][r] += __shfl_xor(racc[qs][r], m);
  if (lr == 0) {
#pragma unroll
    for (int qs = 0; qs < 4; ++qs)
#pragma unroll
      for (int r = 0; r < 4; ++r) red[w][qs * 16 + lg * 4 + r] = racc[qs][r];
  }
  __syncthreads();
  if (tid < 64) {
    float s = red[0][tid] + red[1][tid] + red[2][tid] + red[3][tid];
    s_part[((size_t)(b * 8 + kc) << 12) + q0 + tid] = s;
  }
}

// ---------------- combine partial sums -> invs ----------------
__global__ __launch_bounds__(256) void combine_kernel(const float* __restrict__ s_part,
                                                      float* __restrict__ invs) {
  const int g = blockIdx.x * 256 + threadIdx.x;  // 0..16383
  const int b = g >> 12, q = g & 4095;
  float s = 0.f;
#pragma unroll
  for (int kc = 0; kc < 8; ++kc) s += s_part[((size_t)(b * 8 + kc) << 12) + q];
  invs[g] = 1.f / s;
}

// ---------------- sweep 2: column sums of normalized p, MFMA split-bf16 ----------------
__global__ __launch_bounds__(256) void colsum_kernel2(
    const unsigned short* __restrict__ Qhi, const unsigned short* __restrict__ Qlo,
    const unsigned short* __restrict__ Khi, const unsigned short* __restrict__ Klo,
    const float* __restrict__ invs, float* __restrict__ cs_part) {
  __shared__ float invs_l[512];
  __shared__ float red[4][64];
  const int b = blockIdx.z, qc = blockIdx.y, k0 = blockIdx.x * 64;
  const int tid = threadIdx.x, w = tid >> 6, l = tid & 63;
  const int lr = l & 15, lg = l >> 4;
  const size_t base = (size_t)b * N_PIX;
  for (int v = tid; v < 512; v += 256) invs_l[v] = invs[b * N_PIX + qc * 512 + v];
  short8 kh[4][2], kl[4][2];
#pragma unroll
  for (int ks = 0; ks < 4; ++ks) {
    const size_t koff = (base + k0 + ks * 16 + lr) * 64 + lg * 8;
    kh[ks][0] = *(const short8*)(Khi + koff);
    kh[ks][1] = *(const short8*)(Khi + koff + 32);
    kl[ks][0] = *(const short8*)(Klo + koff);
    kl[ks][1] = *(const short8*)(Klo + koff + 32);
  }
  float kacc[4][4];
#pragma unroll
  for (int ks = 0; ks < 4; ++ks)
#pragma unroll
    for (int r = 0; r < 4; ++r) kacc[ks][r] = 0.f;
  __syncthreads();
  for (int qt = w; qt < 8; qt += 4) {
    const int qb = qc * 512 + qt * 64;
#pragma unroll
    for (int ct = 0; ct < 4; ++ct) {
      const size_t qoff = (base + qb + ct * 16 + lr) * 64 + lg * 8;
      const short8 qh0 = *(const short8*)(Qhi + qoff);
      const short8 qh1 = *(const short8*)(Qhi + qoff + 32);
      const short8 ql0 = *(const short8*)(Qlo + qoff);
      const short8 ql1 = *(const short8*)(Qlo + qoff + 32);
      const float iv = invs_l[qt * 64 + ct * 16 + lr];
#pragma unroll
      for (int ks = 0; ks < 4; ++ks) {
        f32x4 acc = {0.f, 0.f, 0.f, 0.f};
        acc = __builtin_amdgcn_mfma_f32_16x16x32_bf16(kh[ks][0], qh0, acc, 0, 0, 0);
        acc = __builtin_amdgcn_mfma_f32_16x16x32_bf16(kh[ks][1], qh1, acc, 0, 0, 0);
        acc = __builtin_amdgcn_mfma_f32_16x16x32_bf16(kl[ks][0], qh0, acc, 0, 0, 0);
        acc = __builtin_amdgcn_mfma_f32_16x16x32_bf16(kl[ks][1], qh1, acc, 0, 0, 0);
        acc = __builtin_amdgcn_mfma_f32_16x16x32_bf16(kh[ks][0], ql0, acc, 0, 0, 0);
        acc = __builtin_amdgcn_mfma_f32_16x16x32_bf16(kh[ks][1], ql1, acc, 0, 0, 0);
#pragma unroll
        for (int r = 0; r < 4; ++r) kacc[ks][r] += __expf(acc[r] * 0.125f) * iv;
      }
    }
  }
#pragma unroll
  for (int ks = 0; ks < 4; ++ks)
#pragma unroll
    for (int r = 0; r < 4; ++r)
#pragma unroll
      for (int m = 1; m < 16; m <<= 1) kacc[ks][r] += __shfl_xor(kacc[ks][r], m);
  if (lr == 0) {
#pragma unroll
    for (int ks = 0; ks < 4; ++ks)
#pragma unroll
      for (int r = 0; r < 4; ++r) red[w][ks * 16 + lg * 4 + r] = kacc[ks][r];
  }
  __syncthreads();
  if (tid < 64) {
    float s = red[0][tid] + red[1][tid] + red[2][tid] + red[3][tid];
    cs_part[((size_t)(b * 8 + qc) << 12) + k0 + tid] = s;
  }
}

// ---------------- top-128 per batch (iterative argmax, tie -> lowest index) -----------
__global__ __launch_bounds__(256) void topk_kernel(const float* __restrict__ cs_part,
                                                   int* __restrict__ topk) {
  __shared__ float vals[4096];
  __shared__ float bvs[4];
  __shared__ int bis[4];
  __shared__ int bestIdx;
  const int b = blockIdx.x, tid = threadIdx.x;
  for (int v = tid; v < 4096; v += 256) {
    float s = 0.f;
#pragma unroll
    for (int qc = 0; qc < 8; ++qc) s += cs_part[((size_t)(b * 8 + qc) << 12) + v];
    vals[v] = s;
  }
  __syncthreads();
  for (int it = 0; it < 128; ++it) {
    float bvv = -INFINITY;
    int bii = 0x7fffffff;
#pragma unroll
    for (int j = 0; j < 16; ++j) {
      int idx = tid * 16 + j;
      float v = vals[idx];
      if (v > bvv) { bvv = v; bii = idx; }
    }
#pragma unroll
    for (int m = 1; m < 64; m <<= 1) {
      float ov = __shfl_xor(bvv, m);
      int oi = __shfl_xor(bii, m);
      if (ov > bvv || (ov == bvv && oi < bii)) { bvv = ov; bii = oi; }
    }
    if ((tid & 63) == 0) { bvs[tid >> 6] = bvv; bis[tid >> 6] = bii; }
    __syncthreads();
    if (tid == 0) {
      float Bv = bvs[0];
      int Ii = bis[0];
#pragma unroll
      for (int w2 = 1; w2 < 4; ++w2)
        if (bvs[w2] > Bv || (bvs[w2] == Bv && bis[w2] < Ii)) { Bv = bvs[w2]; Ii = bis[w2]; }
      bestIdx = Ii;
      topk[b * 128 + it] = Ii;
    }
    __syncthreads();
    if (tid == (bestIdx >> 4)) vals[bestIdx] = -INFINITY;
    __syncthreads();
  }
}

// 64q x 64k z-tile: z = (Q . K^T) / 8, 4x4 per thread (fp32 path for attn_out)
__device__ __forceinline__ void qk_tile(const float* Ql, const float* Kl, int tx,
                                        int ty, float z[4][4]) {
  float acc[4][4];
#pragma unroll
  for (int i = 0; i < 4; ++i)
#pragma unroll
    for (int j = 0; j < 4; ++j) acc[i][j] = 0.f;
#pragma unroll
  for (int e4 = 0; e4 < 16; ++e4) {
    float4 qa[4], ka[4];
#pragma unroll
    for (int i = 0; i < 4; ++i) qa[i] = *(const float4*)&Ql[swz(ty * 4 + i, e4 * 4)];
#pragma unroll
    for (int j = 0; j < 4; ++j) ka[j] = *(const float4*)&Kl[swz(tx * 4 + j, e4 * 4)];
#pragma unroll
    for (int i = 0; i < 4; ++i)
#pragma unroll
      for (int j = 0; j < 4; ++j)
#pragma unroll
        for (int u = 0; u < 4; ++u)
          acc[i][j] = fmaf(fget(qa[i], u), fget(ka[j], u), acc[i][j]);
  }
#pragma unroll
  for (int i = 0; i < 4; ++i)
#pragma unroll
    for (int j = 0; j < 4; ++j) z[i][j] = acc[i][j] * 0.125f;
}

// ---------------- masked attention output: out1[q,c] = sum_{k in top} p * V ---------
__global__ __launch_bounds__(256) void attn_out_kernel(
    const unsigned short* __restrict__ Qhp, const unsigned short* __restrict__ Qlp,
    const unsigned short* __restrict__ Khp, const unsigned short* __restrict__ Klp,
    const float* __restrict__ Vm, const float* __restrict__ invs,
    const int* __restrict__ topkb, float* __restrict__ out1) {
  __shared__ float Qld[64 * 68], Kld[64 * 68], Vt[64 * 68], Pl[64 * 68];
  __shared__ int sidx[64];
  const int b = blockIdx.y, q0 = blockIdx.x * 64;
  const int tid = threadIdx.x, tx = tid & 15, ty = tid >> 4;
  const size_t base = (size_t)b * N_PIX;
  for (int v = tid; v < 1024; v += 256) {
    int row = v >> 4, c4 = (v & 15) * 4;
    size_t off = (base + q0 + row) * 64 + c4;
    ushort4 h = *(const ushort4*)(Qhp + off);
    ushort4 lo = *(const ushort4*)(Qlp + off);
    float4 f;
    f.x = bf2f(h.x) + bf2f(lo.x);
    f.y = bf2f(h.y) + bf2f(lo.y);
    f.z = bf2f(h.z) + bf2f(lo.z);
    f.w = bf2f(h.w) + bf2f(lo.w);
    *(float4*)&Qld[swz(row, c4)] = f;
  }
  float is[4];
#pragma unroll
  for (int i = 0; i < 4; ++i) is[i] = invs[base + q0 + ty * 4 + i];
  float acc[4][4];
#pragma unroll
  for (int i = 0; i < 4; ++i)
#pragma unroll
    for (int j = 0; j < 4; ++j) acc[i][j] = 0.f;
  for (int ch = 0; ch < 2; ++ch) {
    __syncthreads();
    if (tid < 64) sidx[tid] = topkb[b * 128 + ch * 64 + tid];
    __syncthreads();
    for (int v = tid; v < 1024; v += 256) {
      int row = v >> 4, c4 = (v & 15) * 4;
      size_t off = (base + sidx[row]) * 64 + c4;
      ushort4 h = *(const ushort4*)(Khp + off);
      ushort4 lo = *(const ushort4*)(Klp + off);
      float4 f;
      f.x = bf2f(h.x) + bf2f(lo.x);
      f.y = bf2f(h.y) + bf2f(lo.y);
      f.z = bf2f(h.z) + bf2f(lo.z);
      f.w = bf2f(h.w) + bf2f(lo.w);
      *(float4*)&Kld[swz(row, c4)] = f;
    }
    for (int v = tid; v < 4096; v += 256) {
      int row = v >> 6, c = v & 63;
      Vt[swz(c, row)] = Vm[(base + sidx[row]) * 64 + c];
    }
    __syncthreads();
    float z[4][4];
    qk_tile(Qld, Kld, tx, ty, z);
#pragma unroll
    for (int i = 0; i < 4; ++i)
#pragma unroll
      for (int j = 0; j < 4; ++j)
        Pl[swz(ty * 4 + i, tx * 4 + j)] = __expf(z[i][j]) * is[i];
    __syncthreads();
#pragma unroll
    for (int k4 = 0; k4 < 16; ++k4) {
      float4 pr[4], vr[4];
#pragma unroll
      for (int i = 0; i < 4; ++i) pr[i] = *(const float4*)&Pl[swz(ty * 4 + i, k4 * 4)];
#pragma unroll
      for (int j = 0; j < 4; ++j) vr[j] = *(const float4*)&Vt[swz(tx * 4 + j, k4 * 4)];
#pragma unroll
      for (int i = 0; i < 4; ++i)
#pragma unroll
        for (int j = 0; j < 4; ++j)
#pragma unroll
          for (int u = 0; u < 4; ++u)
            acc[i][j] = fmaf(fget(pr[i], u), fget(vr[j], u), acc[i][j]);
    }
  }
#pragma unroll
  for (int i = 0; i < 4; ++i) {
    float4 o;
    o.x = acc[i][0];
    o.y = acc[i][1];
    o.z = acc[i][2];
    o.w = acc[i][3];
    *(float4*)(out1 + (base + q0 + ty * 4 + i) * 64 + tx * 4) = o;
  }
}

// ---------------- final projection + transpose to [B,C,H,W] ----------------
__global__ __launch_bounds__(256) void proj_kernel(
    const float* __restrict__ out1, const float* __restrict__ wo,
    const float* __restrict__ bo, float* __restrict__ dout) {
  __shared__ float Al[64 * 68], Wl[64 * 68], Yl[64 * 68];
  const int tid = threadIdx.x, tx = tid & 15, ty = tid >> 4;
  const size_t r0 = (size_t)blockIdx.x * 64;
  const int b = (int)(r0 >> 12);
  const int n0 = (int)(r0 & 4095);
  for (int v = tid; v < 1024; v += 256) {
    int row = v >> 4, c4 = (v & 15) * 4;
    *(float4*)&Al[swz(row, c4)] = *(const float4*)(out1 + (r0 + row) * 64 + c4);
    *(float4*)&Wl[swz(row, c4)] = *(const float4*)(wo + row * 64 + c4);
  }
  __syncthreads();
  float acc[4][4];
#pragma unroll
  for (int i = 0; i < 4; ++i)
#pragma unroll
    for (int j = 0; j < 4; ++j) acc[i][j] = 0.f;
#pragma unroll
  for (int e4 = 0; e4 < 16; ++e4) {
    float4 a[4], wr[4];
#pragma unroll
    for (int i = 0; i < 4; ++i) a[i] = *(const float4*)&Al[swz(ty * 4 + i, e4 * 4)];
#pragma unroll
    for (int u = 0; u < 4; ++u) wr[u] = *(const float4*)&Wl[swz(e4 * 4 + u, tx * 4)];
#pragma unroll
    for (int i = 0; i < 4; ++i)
#pragma unroll
      for (int j = 0; j < 4; ++j)
#pragma unroll
        for (int u = 0; u < 4; ++u)
          acc[i][j] = fmaf(fget(a[i], u), fget(wr[u], j), acc[i][j]);
  }
#pragma unroll
  for (int i = 0; i < 4; ++i)
#pragma unroll
    for (int j = 0; j < 4; ++j)
      Yl[swz(ty * 4 + i, tx * 4 + j)] = acc[i][j] + bo[tx * 4 + j];
  __syncthreads();
  for (int v = tid; v < 4096; v += 256) {
    int c = v >> 6, nl = v & 63;
    dout[((size_t)b * 64 + c) * 4096 + n0 + nl] = Yl[swz(nl, c)];
  }
}

extern "C" void kernel_launch(void* const* d_in, const int* in_sizes, int n_in,
                              void* d_out, int out_size, void* d_ws, size_t ws_size,
                              hipStream_t stream) {
  const float* x = (const float*)d_in[0];
  const float* w1 = (const float*)d_in[1];
  const float* b1 = (const float*)d_in[2];
  const float* w3 = (const float*)d_in[3];
  const float* b3 = (const float*)d_in[4];
  const float* w5 = (const float*)d_in[5];
  const float* b5 = (const float*)d_in[6];
  const float* wq = (const float*)d_in[7];
  const float* bq = (const float*)d_in[8];
  const float* wk = (const float*)d_in[9];
  const float* bk = (const float*)d_in[10];
  const float* wv = (const float*)d_in[11];
  const float* bv = (const float*)d_in[12];
  const float* wo = (const float*)d_in[13];
  const float* bo = (const float*)d_in[14];

  const size_t BN = (size_t)4 * N_PIX;  // 16384
  char* p = (char*)d_ws;
  auto carve = [&](size_t bytes) -> void* {
    void* r = (void*)p;
    p += (bytes + 255) & ~(size_t)255;
    return r;
  };
  unsigned short* Bfh = (unsigned short*)carve((size_t)25 * 12 * 2 * 512 * 2);
  unsigned short* Bfl = (unsigned short*)carve((size_t)25 * 12 * 2 * 512 * 2);
  float* beff = (float*)carve(192 * 4);
  float* Vm = (float*)carve(BN * 64 * 4);
  unsigned short* Qhi = (unsigned short*)carve(BN * 64 * 2);
  unsigned short* Qlo = (unsigned short*)carve(BN * 64 * 2);
  unsigned short* Khi = (unsigned short*)carve(BN * 64 * 2);
  unsigned short* Klo = (unsigned short*)carve(BN * 64 * 2);
  float* s_part = (float*)carve((size_t)4 * 8 * 4096 * 4);
  float* invs = (float*)carve(BN * 4);
  float* cs_part = (float*)carve((size_t)4 * 8 * 4096 * 4);
  int* topkbuf = (int*)carve(512 * 4);
  float* out1 = (float*)carve(BN * 64 * 4);

  prep_kernel<<<25, 192, 0, stream>>>(w1, w3, w5, wq, wk, wv, Bfh, Bfl);
  beff_kernel<<<1, 192, 0, stream>>>(b1, b3, b5, bq, bk, bv, wq, wk, wv, beff);
  fused_qkv_kernel<<<dim3(64, 4), 512, 0, stream>>>(x, Bfh, Bfl, beff, Qhi, Qlo, Khi,
                                                    Klo, Vm);
  qk_s_kernel<<<dim3(64, 8, 4), 256, 0, stream>>>(Qhi, Qlo, Khi, Klo, s_part);
  combine_kernel<<<64, 256, 0, stream>>>(s_part, invs);
  colsum_kernel2<<<dim3(64, 8, 4), 256, 0, stream>>>(Qhi, Qlo, Khi, Klo, invs, cs_part);
  topk_kernel<<<4, 256, 0, stream>>>(cs_part, topkbuf);
  attn_out_kernel<<<dim3(64, 4), 256, 0, stream>>>(Qhi, Qlo, Khi, Klo, Vm, invs,
                                                   topkbuf, out1);
  proj_kernel<<<256, 256, 0, stream>>>(out1, wo, bo, (float*)d_out);
}

// Round 4
// 411.818 us; speedup vs baseline: 3.5607x; 3.5607x over previous
//
#include <hip/hip_runtime.h>
#include <math.h>

#define N_PIX 4096
#define CCH 64

typedef __attribute__((ext_vector_type(8))) short short8;
typedef __attribute__((ext_vector_type(4))) float f32x4;

// LDS tiles are [rows][68] floats; XOR-swizzle the 4-float granule by (row>>2)&7
// so that 4-row-strided b128 reads spread across bank groups (else 8-way conflict).
__device__ __forceinline__ int swz(int row, int col) {
  return row * 68 + (col ^ (((row >> 2) & 7) << 2));
}

__device__ __forceinline__ float fget(const float4& v, int j) {
  return ((const float*)&v)[j];
}

__device__ __forceinline__ unsigned short f2bf(float f) {
  unsigned u = __float_as_uint(f);
  unsigned r = (u + 0x7fff + ((u >> 16) & 1)) >> 16;
  return (unsigned short)r;
}
__device__ __forceinline__ float bf2f(unsigned short h) {
  return __uint_as_float((unsigned)h << 16);
}

// ---------------- weight prep: fold conv weights into wq|wk|wv ----------------
// Weff[t*64+i][e] = sum_o w5[o,i,t]*Wcat[128+o][e] + (inner) w3[o,i,t3]*Wcat[64+o][e]
//                 + (center) w1[o,i]*Wcat[o][e],  Wcat = [wq | wk | wv].
// Tiled GEMM: grid (which, tap), block 256, output tile 64 i x 64 em.
// Epilogue writes MFMA B-fragment order: frag f=(t*12+q)*2+s holds
// B[k=t*64+s*32+(lane>>4)*8+j][e=q*16+(lane&15)] at Bf[f*512 + lane*8 + j].
__global__ __launch_bounds__(256) void prep_kernel(
    const float* __restrict__ w1, const float* __restrict__ w3,
    const float* __restrict__ w5, const float* __restrict__ wq,
    const float* __restrict__ wk, const float* __restrict__ wv,
    unsigned short* __restrict__ Bfh, unsigned short* __restrict__ Bfl) {
  __shared__ float At[64 * 68];  // A[i][o] = wconv[o,i,tap]
  __shared__ float Bt[64 * 68];  // B[o][em] = Wsel[rowbase+o][em]
  const int which = blockIdx.x, t = blockIdx.y;
  const int ky = t / 5, kx = t % 5;
  const float* Wsel = which == 0 ? wq : (which == 1 ? wk : wv);
  const bool in3 = (ky >= 1 && ky <= 3 && kx >= 1 && kx <= 3);
  const bool c1 = (t == 12);
  const int t3 = (ky - 1) * 3 + (kx - 1);
  const int tid = threadIdx.x, tx = tid & 15, ty = tid >> 4;
  float acc[4][4];
#pragma unroll
  for (int i = 0; i < 4; ++i)
#pragma unroll
    for (int j = 0; j < 4; ++j) acc[i][j] = 0.f;
  const int npass = 1 + (in3 ? 1 : 0) + (c1 ? 1 : 0);
  for (int pass = 0; pass < npass; ++pass) {
    // pass 0: w5 vs rows 128..191; pass 1: w3 vs 64..127 (or w1 if !in3); pass 2: w1
    const int kind = pass == 0 ? 0 : (pass == 1 && in3 ? 1 : 2);
    const int rowbase = kind == 0 ? 128 : (kind == 1 ? 64 : 0);
    __syncthreads();
    for (int v = tid; v < 4096; v += 256) {
      const int i = v & 63, o = v >> 6;
      float a;
      if (kind == 0) a = w5[(size_t)(o * 64 + i) * 25 + t];
      else if (kind == 1) a = w3[(size_t)(o * 64 + i) * 9 + t3];
      else a = w1[o * 64 + i];
      At[swz(i, o)] = a;
    }
    for (int v = tid; v < 1024; v += 256) {
      const int row = v >> 4, c4 = (v & 15) * 4;
      *(float4*)&Bt[swz(row, c4)] = *(const float4*)(Wsel + (rowbase + row) * 64 + c4);
    }
    __syncthreads();
#pragma unroll
    for (int o4 = 0; o4 < 16; ++o4) {
      float4 a[4], b[4];
#pragma unroll
      for (int i = 0; i < 4; ++i) a[i] = *(const float4*)&At[swz(ty * 4 + i, o4 * 4)];
#pragma unroll
      for (int u = 0; u < 4; ++u) b[u] = *(const float4*)&Bt[swz(o4 * 4 + u, tx * 4)];
#pragma unroll
      for (int i = 0; i < 4; ++i)
#pragma unroll
        for (int j = 0; j < 4; ++j)
#pragma unroll
          for (int u = 0; u < 4; ++u)
            acc[i][j] = fmaf(fget(a[i], u), fget(b[u], j), acc[i][j]);
    }
  }
  // epilogue: scatter into B-fragment order with hi/lo split
#pragma unroll
  for (int ii = 0; ii < 4; ++ii) {
    const int i = ty * 4 + ii;
    const int s = i >> 5, lg = (i >> 3) & 3, j = i & 7;
#pragma unroll
    for (int jj = 0; jj < 4; ++jj) {
      const int em = tx * 4 + jj;
      const int q = which * 4 + (em >> 4), lr = em & 15;
      const size_t off = ((size_t)(t * 12 + q) * 2 + s) * 512 + (lg * 16 + lr) * 8 + j;
      const float val = acc[ii][jj];
      const unsigned short h = f2bf(val);
      Bfh[off] = h;
      Bfl[off] = f2bf(val - bf2f(h));
    }
  }
}

// effective bias: beff[e] = bcat[e] + sum_row bconv[row] * Wcat[row][e]
__global__ __launch_bounds__(192) void beff_kernel(
    const float* __restrict__ b1, const float* __restrict__ b3,
    const float* __restrict__ b5, const float* __restrict__ bq,
    const float* __restrict__ bk, const float* __restrict__ bv,
    const float* __restrict__ wq, const float* __restrict__ wk,
    const float* __restrict__ wv, float* __restrict__ beff) {
  const int e = threadIdx.x;
  const int em = e & 63, which = e >> 6;
  const float* Wsel = which == 0 ? wq : (which == 1 ? wk : wv);
  const float* bsel = which == 0 ? bq : (which == 1 ? bk : bv);
  float s = bsel[em];
  for (int row = 0; row < 192; ++row) {
    const float bc = row < 64 ? b1[row] : (row < 128 ? b3[row - 64] : b5[row - 128]);
    s += bc * Wsel[row * 64 + em];
  }
  beff[e] = s;
}

// ---------------- fused im2col GEMM: x -> Q(hi/lo), K(hi/lo), V ----------------
// Block: 64 pixels (8x8 spatial) x 192 outputs. 8 waves: wave = (half, pg);
// wave handles pixel-group pg (16 pixels), output quadrants half*6..half*6+5.
__global__ __launch_bounds__(512) void fused_qkv_kernel(
    const float* __restrict__ x, const unsigned short* __restrict__ Bfh,
    const unsigned short* __restrict__ Bfl, const float* __restrict__ beff,
    unsigned short* __restrict__ Qhi, unsigned short* __restrict__ Qlo,
    unsigned short* __restrict__ Khi, unsigned short* __restrict__ Klo,
    float* __restrict__ Vm) {
  __shared__ unsigned short Lh[144 * 64];
  __shared__ unsigned short Ll[144 * 64];
  const int b = blockIdx.y;
  const int sb = blockIdx.x;
  const int y0 = (sb >> 3) * 8, x0 = (sb & 7) * 8;
  const int tid = threadIdx.x;
  const int l = tid & 63, lr = l & 15, lg = l >> 4;
  const int pg = (tid >> 6) & 3, half6 = (tid >> 8) * 6;
  const float* xb = x + (size_t)b * CCH * N_PIX;
  // stage 12x12x64 patch as bf16 hi/lo, XOR-swizzled on the 8-ch granule
  for (int it = 0; it < 18; ++it) {
    const int idx = it * 512 + tid;
    const int c = idx / 144;
    const int pr = idx - c * 144;
    const int py = pr / 12, px = pr - py * 12;
    const int gy = y0 - 2 + py, gx = x0 - 2 + px;
    float v = 0.f;
    if (gy >= 0 && gy < 64 && gx >= 0 && gx < 64) v = xb[c * N_PIX + gy * 64 + gx];
    const unsigned short h = f2bf(v);
    const int a = pr * 64 + (c ^ ((pr & 7) << 3));
    Lh[a] = h;
    Ll[a] = f2bf(v - bf2f(h));
  }
  __syncthreads();
  const int p = pg * 16 + lr;  // this lane's A-row pixel
  const int prp = (p >> 3) * 12 + (p & 7);
  f32x4 acc[6];
#pragma unroll
  for (int q6 = 0; q6 < 6; ++q6) acc[q6] = (f32x4){0.f, 0.f, 0.f, 0.f};
  for (int ky = 0; ky < 5; ++ky) {
    for (int kx = 0; kx < 5; ++kx) {
      const int t = ky * 5 + kx;
      const int prt = prp + ky * 12 + kx;
      const int rb = prt * 64, sw = (prt & 7) << 3;
      const short8 ah0 = *(const short8*)&Lh[rb + ((lg << 3) ^ sw)];
      const short8 ah1 = *(const short8*)&Lh[rb + ((32 + (lg << 3)) ^ sw)];
      const short8 al0 = *(const short8*)&Ll[rb + ((lg << 3) ^ sw)];
      const short8 al1 = *(const short8*)&Ll[rb + ((32 + (lg << 3)) ^ sw)];
#pragma unroll
      for (int q6 = 0; q6 < 6; ++q6) {
        const size_t f = ((size_t)(t * 12 + half6 + q6)) * 2;
        const short8 bh0 = *(const short8*)&Bfh[f * 512 + l * 8];
        const short8 bh1 = *(const short8*)&Bfh[(f + 1) * 512 + l * 8];
        const short8 bl0 = *(const short8*)&Bfl[f * 512 + l * 8];
        const short8 bl1 = *(const short8*)&Bfl[(f + 1) * 512 + l * 8];
        acc[q6] = __builtin_amdgcn_mfma_f32_16x16x32_bf16(ah0, bh0, acc[q6], 0, 0, 0);
        acc[q6] = __builtin_amdgcn_mfma_f32_16x16x32_bf16(ah1, bh1, acc[q6], 0, 0, 0);
        acc[q6] = __builtin_amdgcn_mfma_f32_16x16x32_bf16(al0, bh0, acc[q6], 0, 0, 0);
        acc[q6] = __builtin_amdgcn_mfma_f32_16x16x32_bf16(al1, bh1, acc[q6], 0, 0, 0);
        acc[q6] = __builtin_amdgcn_mfma_f32_16x16x32_bf16(ah0, bl0, acc[q6], 0, 0, 0);
        acc[q6] = __builtin_amdgcn_mfma_f32_16x16x32_bf16(ah1, bl1, acc[q6], 0, 0, 0);
      }
    }
  }
  // epilogue: D col = l&15 -> e, row = lg*4+r -> pixel
  const size_t base = (size_t)b * N_PIX;
#pragma unroll
  for (int q6 = 0; q6 < 6; ++q6) {
    const int e = (half6 + q6) * 16 + lr;
    const int which = e >> 6, em = e & 63;
    const float be = beff[e];
#pragma unroll
    for (int r = 0; r < 4; ++r) {
      const int pp = pg * 16 + lg * 4 + r;
      const int n = (y0 + (pp >> 3)) * 64 + x0 + (pp & 7);
      const float val = acc[q6][r] + be;
      const size_t off = (base + n) * 64 + em;
      if (which == 2) {
        Vm[off] = val;
      } else {
        const unsigned short h = f2bf(val);
        const unsigned short lo = f2bf(val - bf2f(h));
        if (which == 0) {
          Qhi[off] = h;
          Qlo[off] = lo;
        } else {
          Khi[off] = h;
          Klo[off] = lo;
        }
      }
    }
  }
}

// ---------------- sweep 1: partial row sums of exp(z), MFMA split-bf16 ----------------
__global__ __launch_bounds__(256) void qk_s_kernel(
    const unsigned short* __restrict__ Qhi, const unsigned short* __restrict__ Qlo,
    const unsigned short* __restrict__ Khi, const unsigned short* __restrict__ Klo,
    float* __restrict__ s_part) {
  __shared__ float red[4][64];
  const int b = blockIdx.z, kc = blockIdx.y, q0 = blockIdx.x * 64;
  const int tid = threadIdx.x, w = tid >> 6, l = tid & 63;
  const int lr = l & 15, lg = l >> 4;
  const size_t base = (size_t)b * N_PIX;
  short8 qh[4][2], ql[4][2];
#pragma unroll
  for (int qs = 0; qs < 4; ++qs) {
    const size_t qoff = (base + q0 + qs * 16 + lr) * 64 + lg * 8;
    qh[qs][0] = *(const short8*)(Qhi + qoff);
    qh[qs][1] = *(const short8*)(Qhi + qoff + 32);
    ql[qs][0] = *(const short8*)(Qlo + qoff);
    ql[qs][1] = *(const short8*)(Qlo + qoff + 32);
  }
  float racc[4][4];
#pragma unroll
  for (int qs = 0; qs < 4; ++qs)
#pragma unroll
    for (int r = 0; r < 4; ++r) racc[qs][r] = 0.f;
  for (int kt = w; kt < 8; kt += 4) {
    const int kb = kc * 512 + kt * 64;
#pragma unroll
    for (int ct = 0; ct < 4; ++ct) {
      const size_t koff = (base + kb + ct * 16 + lr) * 64 + lg * 8;
      const short8 kh0 = *(const short8*)(Khi + koff);
      const short8 kh1 = *(const short8*)(Khi + koff + 32);
      const short8 kl0 = *(const short8*)(Klo + koff);
      const short8 kl1 = *(const short8*)(Klo + koff + 32);
#pragma unroll
      for (int qs = 0; qs < 4; ++qs) {
        f32x4 acc = {0.f, 0.f, 0.f, 0.f};
        acc = __builtin_amdgcn_mfma_f32_16x16x32_bf16(qh[qs][0], kh0, acc, 0, 0, 0);
        acc = __builtin_amdgcn_mfma_f32_16x16x32_bf16(qh[qs][1], kh1, acc, 0, 0, 0);
        acc = __builtin_amdgcn_mfma_f32_16x16x32_bf16(ql[qs][0], kh0, acc, 0, 0, 0);
        acc = __builtin_amdgcn_mfma_f32_16x16x32_bf16(ql[qs][1], kh1, acc, 0, 0, 0);
        acc = __builtin_amdgcn_mfma_f32_16x16x32_bf16(qh[qs][0], kl0, acc, 0, 0, 0);
        acc = __builtin_amdgcn_mfma_f32_16x16x32_bf16(qh[qs][1], kl1, acc, 0, 0, 0);
#pragma unroll
        for (int r = 0; r < 4; ++r) racc[qs][r] += __expf(acc[r] * 0.125f);
      }
    }
  }
#pragma unroll
  for (int qs = 0; qs < 4; ++qs)
#pragma unroll
    for (int r = 0; r < 4; ++r)
#pragma unroll
      for (int m = 1; m < 16; m <<= 1) racc[qs][r] += __shfl_xor(racc[qs][r], m);
  if (lr == 0) {
#pragma unroll
    for (int qs = 0; qs < 4; ++qs)
#pragma unroll
      for (int r = 0; r < 4; ++r) red[w][qs * 16 + lg * 4 + r] = racc[qs][r];
  }
  __syncthreads();
  if (tid < 64) {
    float s = red[0][tid] + red[1][tid] + red[2][tid] + red[3][tid];
    s_part[((size_t)(b * 8 + kc) << 12) + q0 + tid] = s;
  }
}

// ---------------- combine partial sums -> invs ----------------
__global__ __launch_bounds__(256) void combine_kernel(const float* __restrict__ s_part,
                                                      float* __restrict__ invs) {
  const int g = blockIdx.x * 256 + threadIdx.x;  // 0..16383
  const int b = g >> 12, q = g & 4095;
  float s = 0.f;
#pragma unroll
  for (int kc = 0; kc < 8; ++kc) s += s_part[((size_t)(b * 8 + kc) << 12) + q];
  invs[g] = 1.f / s;
}

// ---------------- sweep 2: column sums of normalized p, MFMA split-bf16 ----------------
__global__ __launch_bounds__(256) void colsum_kernel2(
    const unsigned short* __restrict__ Qhi, const unsigned short* __restrict__ Qlo,
    const unsigned short* __restrict__ Khi, const unsigned short* __restrict__ Klo,
    const float* __restrict__ invs, float* __restrict__ cs_part) {
  __shared__ float invs_l[512];
  __shared__ float red[4][64];
  const int b = blockIdx.z, qc = blockIdx.y, k0 = blockIdx.x * 64;
  const int tid = threadIdx.x, w = tid >> 6, l = tid & 63;
  const int lr = l & 15, lg = l >> 4;
  const size_t base = (size_t)b * N_PIX;
  for (int v = tid; v < 512; v += 256) invs_l[v] = invs[b * N_PIX + qc * 512 + v];
  short8 kh[4][2], kl[4][2];
#pragma unroll
  for (int ks = 0; ks < 4; ++ks) {
    const size_t koff = (base + k0 + ks * 16 + lr) * 64 + lg * 8;
    kh[ks][0] = *(const short8*)(Khi + koff);
    kh[ks][1] = *(const short8*)(Khi + koff + 32);
    kl[ks][0] = *(const short8*)(Klo + koff);
    kl[ks][1] = *(const short8*)(Klo + koff + 32);
  }
  float kacc[4][4];
#pragma unroll
  for (int ks = 0; ks < 4; ++ks)
#pragma unroll
    for (int r = 0; r < 4; ++r) kacc[ks][r] = 0.f;
  __syncthreads();
  for (int qt = w; qt < 8; qt += 4) {
    const int qb = qc * 512 + qt * 64;
#pragma unroll
    for (int ct = 0; ct < 4; ++ct) {
      const size_t qoff = (base + qb + ct * 16 + lr) * 64 + lg * 8;
      const short8 qh0 = *(const short8*)(Qhi + qoff);
      const short8 qh1 = *(const short8*)(Qhi + qoff + 32);
      const short8 ql0 = *(const short8*)(Qlo + qoff);
      const short8 ql1 = *(const short8*)(Qlo + qoff + 32);
      const float iv = invs_l[qt * 64 + ct * 16 + lr];
#pragma unroll
      for (int ks = 0; ks < 4; ++ks) {
        f32x4 acc = {0.f, 0.f, 0.f, 0.f};
        acc = __builtin_amdgcn_mfma_f32_16x16x32_bf16(kh[ks][0], qh0, acc, 0, 0, 0);
        acc = __builtin_amdgcn_mfma_f32_16x16x32_bf16(kh[ks][1], qh1, acc, 0, 0, 0);
        acc = __builtin_amdgcn_mfma_f32_16x16x32_bf16(kl[ks][0], qh0, acc, 0, 0, 0);
        acc = __builtin_amdgcn_mfma_f32_16x16x32_bf16(kl[ks][1], qh1, acc, 0, 0, 0);
        acc = __builtin_amdgcn_mfma_f32_16x16x32_bf16(kh[ks][0], ql0, acc, 0, 0, 0);
        acc = __builtin_amdgcn_mfma_f32_16x16x32_bf16(kh[ks][1], ql1, acc, 0, 0, 0);
#pragma unroll
        for (int r = 0; r < 4; ++r) kacc[ks][r] += __expf(acc[r] * 0.125f) * iv;
      }
    }
  }
#pragma unroll
  for (int ks = 0; ks < 4; ++ks)
#pragma unroll
    for (int r = 0; r < 4; ++r)
#pragma unroll
      for (int m = 1; m < 16; m <<= 1) kacc[ks][r] += __shfl_xor(kacc[ks][r], m);
  if (lr == 0) {
#pragma unroll
    for (int ks = 0; ks < 4; ++ks)
#pragma unroll
      for (int r = 0; r < 4; ++r) red[w][ks * 16 + lg * 4 + r] = kacc[ks][r];
  }
  __syncthreads();
  if (tid < 64) {
    float s = red[0][tid] + red[1][tid] + red[2][tid] + red[3][tid];
    cs_part[((size_t)(b * 8 + qc) << 12) + k0 + tid] = s;
  }
}

// ---------------- top-128 per batch (iterative argmax, tie -> lowest index) -----------
__global__ __launch_bounds__(256) void topk_kernel(const float* __restrict__ cs_part,
                                                   int* __restrict__ topk) {
  __shared__ float vals[4096];
  __shared__ float bvs[4];
  __shared__ int bis[4];
  __shared__ int bestIdx;
  const int b = blockIdx.x, tid = threadIdx.x;
  for (int v = tid; v < 4096; v += 256) {
    float s = 0.f;
#pragma unroll
    for (int qc = 0; qc < 8; ++qc) s += cs_part[((size_t)(b * 8 + qc) << 12) + v];
    vals[v] = s;
  }
  __syncthreads();
  for (int it = 0; it < 128; ++it) {
    float bvv = -INFINITY;
    int bii = 0x7fffffff;
#pragma unroll
    for (int j = 0; j < 16; ++j) {
      int idx = tid * 16 + j;
      float v = vals[idx];
      if (v > bvv) { bvv = v; bii = idx; }
    }
#pragma unroll
    for (int m = 1; m < 64; m <<= 1) {
      float ov = __shfl_xor(bvv, m);
      int oi = __shfl_xor(bii, m);
      if (ov > bvv || (ov == bvv && oi < bii)) { bvv = ov; bii = oi; }
    }
    if ((tid & 63) == 0) { bvs[tid >> 6] = bvv; bis[tid >> 6] = bii; }
    __syncthreads();
    if (tid == 0) {
      float Bv = bvs[0];
      int Ii = bis[0];
#pragma unroll
      for (int w2 = 1; w2 < 4; ++w2)
        if (bvs[w2] > Bv || (bvs[w2] == Bv && bis[w2] < Ii)) { Bv = bvs[w2]; Ii = bis[w2]; }
      bestIdx = Ii;
      topk[b * 128 + it] = Ii;
    }
    __syncthreads();
    if (tid == (bestIdx >> 4)) vals[bestIdx] = -INFINITY;
    __syncthreads();
  }
}

// 64q x 64k z-tile: z = (Q . K^T) / 8, 4x4 per thread (fp32 path for attn_out)
__device__ __forceinline__ void qk_tile(const float* Ql, const float* Kl, int tx,
                                        int ty, float z[4][4]) {
  float acc[4][4];
#pragma unroll
  for (int i = 0; i < 4; ++i)
#pragma unroll
    for (int j = 0; j < 4; ++j) acc[i][j] = 0.f;
#pragma unroll
  for (int e4 = 0; e4 < 16; ++e4) {
    float4 qa[4], ka[4];
#pragma unroll
    for (int i = 0; i < 4; ++i) qa[i] = *(const float4*)&Ql[swz(ty * 4 + i, e4 * 4)];
#pragma unroll
    for (int j = 0; j < 4; ++j) ka[j] = *(const float4*)&Kl[swz(tx * 4 + j, e4 * 4)];
#pragma unroll
    for (int i = 0; i < 4; ++i)
#pragma unroll
      for (int j = 0; j < 4; ++j)
#pragma unroll
        for (int u = 0; u < 4; ++u)
          acc[i][j] = fmaf(fget(qa[i], u), fget(ka[j], u), acc[i][j]);
  }
#pragma unroll
  for (int i = 0; i < 4; ++i)
#pragma unroll
    for (int j = 0; j < 4; ++j) z[i][j] = acc[i][j] * 0.125f;
}

// ---------------- masked attention output: out1[q,c] = sum_{k in top} p * V ---------
__global__ __launch_bounds__(256) void attn_out_kernel(
    const unsigned short* __restrict__ Qhp, const unsigned short* __restrict__ Qlp,
    const unsigned short* __restrict__ Khp, const unsigned short* __restrict__ Klp,
    const float* __restrict__ Vm, const float* __restrict__ invs,
    const int* __restrict__ topkb, float* __restrict__ out1) {
  __shared__ float Qld[64 * 68], Kld[64 * 68], Vt[64 * 68], Pl[64 * 68];
  __shared__ int sidx[64];
  const int b = blockIdx.y, q0 = blockIdx.x * 64;
  const int tid = threadIdx.x, tx = tid & 15, ty = tid >> 4;
  const size_t base = (size_t)b * N_PIX;
  for (int v = tid; v < 1024; v += 256) {
    int row = v >> 4, c4 = (v & 15) * 4;
    size_t off = (base + q0 + row) * 64 + c4;
    ushort4 h = *(const ushort4*)(Qhp + off);
    ushort4 lo = *(const ushort4*)(Qlp + off);
    float4 f;
    f.x = bf2f(h.x) + bf2f(lo.x);
    f.y = bf2f(h.y) + bf2f(lo.y);
    f.z = bf2f(h.z) + bf2f(lo.z);
    f.w = bf2f(h.w) + bf2f(lo.w);
    *(float4*)&Qld[swz(row, c4)] = f;
  }
  float is[4];
#pragma unroll
  for (int i = 0; i < 4; ++i) is[i] = invs[base + q0 + ty * 4 + i];
  float acc[4][4];
#pragma unroll
  for (int i = 0; i < 4; ++i)
#pragma unroll
    for (int j = 0; j < 4; ++j) acc[i][j] = 0.f;
  for (int ch = 0; ch < 2; ++ch) {
    __syncthreads();
    if (tid < 64) sidx[tid] = topkb[b * 128 + ch * 64 + tid];
    __syncthreads();
    for (int v = tid; v < 1024; v += 256) {
      int row = v >> 4, c4 = (v & 15) * 4;
      size_t off = (base + sidx[row]) * 64 + c4;
      ushort4 h = *(const ushort4*)(Khp + off);
      ushort4 lo = *(const ushort4*)(Klp + off);
      float4 f;
      f.x = bf2f(h.x) + bf2f(lo.x);
      f.y = bf2f(h.y) + bf2f(lo.y);
      f.z = bf2f(h.z) + bf2f(lo.z);
      f.w = bf2f(h.w) + bf2f(lo.w);
      *(float4*)&Kld[swz(row, c4)] = f;
    }
    for (int v = tid; v < 4096; v += 256) {
      int row = v >> 6, c = v & 63;
      Vt[swz(c, row)] = Vm[(base + sidx[row]) * 64 + c];
    }
    __syncthreads();
    float z[4][4];
    qk_tile(Qld, Kld, tx, ty, z);
#pragma unroll
    for (int i = 0; i < 4; ++i)
#pragma unroll
      for (int j = 0; j < 4; ++j)
        Pl[swz(ty * 4 + i, tx * 4 + j)] = __expf(z[i][j]) * is[i];
    __syncthreads();
#pragma unroll
    for (int k4 = 0; k4 < 16; ++k4) {
      float4 pr[4], vr[4];
#pragma unroll
      for (int i = 0; i < 4; ++i) pr[i] = *(const float4*)&Pl[swz(ty * 4 + i, k4 * 4)];
#pragma unroll
      for (int j = 0; j < 4; ++j) vr[j] = *(const float4*)&Vt[swz(tx * 4 + j, k4 * 4)];
#pragma unroll
      for (int i = 0; i < 4; ++i)
#pragma unroll
        for (int j = 0; j < 4; ++j)
#pragma unroll
          for (int u = 0; u < 4; ++u)
            acc[i][j] = fmaf(fget(pr[i], u), fget(vr[j], u), acc[i][j]);
    }
  }
#pragma unroll
  for (int i = 0; i < 4; ++i) {
    float4 o;
    o.x = acc[i][0];
    o.y = acc[i][1];
    o.z = acc[i][2];
    o.w = acc[i][3];
    *(float4*)(out1 + (base + q0 + ty * 4 + i) * 64 + tx * 4) = o;
  }
}

// ---------------- final projection + transpose to [B,C,H,W] ----------------
__global__ __launch_bounds__(256) void proj_kernel(
    const float* __restrict__ out1, const float* __restrict__ wo,
    const float* __restrict__ bo, float* __restrict__ dout) {
  __shared__ float Al[64 * 68], Wl[64 * 68], Yl[64 * 68];
  const int tid = threadIdx.x, tx = tid & 15, ty = tid >> 4;
  const size_t r0 = (size_t)blockIdx.x * 64;
  const int b = (int)(r0 >> 12);
  const int n0 = (int)(r0 & 4095);
  for (int v = tid; v < 1024; v += 256) {
    int row = v >> 4, c4 = (v & 15) * 4;
    *(float4*)&Al[swz(row, c4)] = *(const float4*)(out1 + (r0 + row) * 64 + c4);
    *(float4*)&Wl[swz(row, c4)] = *(const float4*)(wo + row * 64 + c4);
  }
  __syncthreads();
  float acc[4][4];
#pragma unroll
  for (int i = 0; i < 4; ++i)
#pragma unroll
    for (int j = 0; j < 4; ++j) acc[i][j] = 0.f;
#pragma unroll
  for (int e4 = 0; e4 < 16; ++e4) {
    float4 a[4], wr[4];
#pragma unroll
    for (int i = 0; i < 4; ++i) a[i] = *(const float4*)&Al[swz(ty * 4 + i, e4 * 4)];
#pragma unroll
    for (int u = 0; u < 4; ++u) wr[u] = *(const float4*)&Wl[swz(e4 * 4 + u, tx * 4)];
#pragma unroll
    for (int i = 0; i < 4; ++i)
#pragma unroll
      for (int j = 0; j < 4; ++j)
#pragma unroll
        for (int u = 0; u < 4; ++u)
          acc[i][j] = fmaf(fget(a[i], u), fget(wr[u], j), acc[i][j]);
  }
#pragma unroll
  for (int i = 0; i < 4; ++i)
#pragma unroll
    for (int j = 0; j < 4; ++j)
      Yl[swz(ty * 4 + i, tx * 4 + j)] = acc[i][j] + bo[tx * 4 + j];
  __syncthreads();
  for (int v = tid; v < 4096; v += 256) {
    int c = v >> 6, nl = v & 63;
    dout[((size_t)b * 64 + c) * 4096 + n0 + nl] = Yl[swz(nl, c)];
  }
}

extern "C" void kernel_launch(void* const* d_in, const int* in_sizes, int n_in,
                              void* d_out, int out_size, void* d_ws, size_t ws_size,
                              hipStream_t stream) {
  const float* x = (const float*)d_in[0];
  const float* w1 = (const float*)d_in[1];
  const float* b1 = (const float*)d_in[2];
  const float* w3 = (const float*)d_in[3];
  const float* b3 = (const float*)d_in[4];
  const float* w5 = (const float*)d_in[5];
  const float* b5 = (const float*)d_in[6];
  const float* wq = (const float*)d_in[7];
  const float* bq = (const float*)d_in[8];
  const float* wk = (const float*)d_in[9];
  const float* bk = (const float*)d_in[10];
  const float* wv = (const float*)d_in[11];
  const float* bv = (const float*)d_in[12];
  const float* wo = (const float*)d_in[13];
  const float* bo = (const float*)d_in[14];

  const size_t BN = (size_t)4 * N_PIX;  // 16384
  char* p = (char*)d_ws;
  auto carve = [&](size_t bytes) -> void* {
    void* r = (void*)p;
    p += (bytes + 255) & ~(size_t)255;
    return r;
  };
  unsigned short* Bfh = (unsigned short*)carve((size_t)25 * 12 * 2 * 512 * 2);
  unsigned short* Bfl = (unsigned short*)carve((size_t)25 * 12 * 2 * 512 * 2);
  float* beff = (float*)carve(192 * 4);
  float* Vm = (float*)carve(BN * 64 * 4);
  unsigned short* Qhi = (unsigned short*)carve(BN * 64 * 2);
  unsigned short* Qlo = (unsigned short*)carve(BN * 64 * 2);
  unsigned short* Khi = (unsigned short*)carve(BN * 64 * 2);
  unsigned short* Klo = (unsigned short*)carve(BN * 64 * 2);
  float* s_part = (float*)carve((size_t)4 * 8 * 4096 * 4);
  float* invs = (float*)carve(BN * 4);
  float* cs_part = (float*)carve((size_t)4 * 8 * 4096 * 4);
  int* topkbuf = (int*)carve(512 * 4);
  float* out1 = (float*)carve(BN * 64 * 4);

  prep_kernel<<<dim3(3, 25), 256, 0, stream>>>(w1, w3, w5, wq, wk, wv, Bfh, Bfl);
  beff_kernel<<<1, 192, 0, stream>>>(b1, b3, b5, bq, bk, bv, wq, wk, wv, beff);
  fused_qkv_kernel<<<dim3(64, 4), 512, 0, stream>>>(x, Bfh, Bfl, beff, Qhi, Qlo, Khi,
                                                    Klo, Vm);
  qk_s_kernel<<<dim3(64, 8, 4), 256, 0, stream>>>(Qhi, Qlo, Khi, Klo, s_part);
  combine_kernel<<<64, 256, 0, stream>>>(s_part, invs);
  colsum_kernel2<<<dim3(64, 8, 4), 256, 0, stream>>>(Qhi, Qlo, Khi, Klo, invs, cs_part);
  topk_kernel<<<4, 256, 0, stream>>>(cs_part, topkbuf);
  attn_out_kernel<<<dim3(64, 4), 256, 0, stream>>>(Qhi, Qlo, Khi, Klo, Vm, invs,
                                                   topkbuf, out1);
  proj_kernel<<<256, 256, 0, stream>>>(out1, wo, bo, (float*)d_out);
}

// Round 5
// 274.541 us; speedup vs baseline: 5.3411x; 1.5000x over previous
//
#include <hip/hip_runtime.h>
#include <math.h>

#define N_PIX 4096
#define CCH 64

typedef __attribute__((ext_vector_type(8))) short short8;
typedef __attribute__((ext_vector_type(4))) float f32x4;

// LDS tiles are [rows][68] floats; XOR-swizzle the 4-float granule by (row>>2)&7
// so that 4-row-strided b128 reads spread across bank groups (else 8-way conflict).
__device__ __forceinline__ int swz(int row, int col) {
  return row * 68 + (col ^ (((row >> 2) & 7) << 2));
}

__device__ __forceinline__ float fget(const float4& v, int j) {
  return ((const float*)&v)[j];
}

__device__ __forceinline__ unsigned short f2bf(float f) {
  unsigned u = __float_as_uint(f);
  unsigned r = (u + 0x7fff + ((u >> 16) & 1)) >> 16;
  return (unsigned short)r;
}
__device__ __forceinline__ float bf2f(unsigned short h) {
  return __uint_as_float((unsigned)h << 16);
}

// ---------------- weight prep: fold conv weights into wq|wk|wv ----------------
// Weff[t*64+i][e] = sum_o w5[o,i,t]*Wcat[128+o][e] + (inner) w3[o,i,t3]*Wcat[64+o][e]
//                 + (center) w1[o,i]*Wcat[o][e],  Wcat = [wq | wk | wv].
// Tiled GEMM: grid (which, tap), block 256, output tile 64 i x 64 em.
// Epilogue writes MFMA B-fragment order: frag f=(t*12+q)*2+s holds
// B[k=t*64+s*32+(lane>>4)*8+j][e=q*16+(lane&15)] at Bf[f*512 + lane*8 + j].
__global__ __launch_bounds__(256) void prep_kernel(
    const float* __restrict__ w1, const float* __restrict__ w3,
    const float* __restrict__ w5, const float* __restrict__ wq,
    const float* __restrict__ wk, const float* __restrict__ wv,
    unsigned short* __restrict__ Bfh, unsigned short* __restrict__ Bfl) {
  __shared__ float At[64 * 68];  // A[i][o] = wconv[o,i,tap]
  __shared__ float Bt[64 * 68];  // B[o][em] = Wsel[rowbase+o][em]
  const int which = blockIdx.x, t = blockIdx.y;
  const int ky = t / 5, kx = t % 5;
  const float* Wsel = which == 0 ? wq : (which == 1 ? wk : wv);
  const bool in3 = (ky >= 1 && ky <= 3 && kx >= 1 && kx <= 3);
  const bool c1 = (t == 12);
  const int t3 = (ky - 1) * 3 + (kx - 1);
  const int tid = threadIdx.x, tx = tid & 15, ty = tid >> 4;
  float acc[4][4];
#pragma unroll
  for (int i = 0; i < 4; ++i)
#pragma unroll
    for (int j = 0; j < 4; ++j) acc[i][j] = 0.f;
  const int npass = 1 + (in3 ? 1 : 0) + (c1 ? 1 : 0);
  for (int pass = 0; pass < npass; ++pass) {
    // pass 0: w5 vs rows 128..191; pass 1: w3 vs 64..127 (or w1 if !in3); pass 2: w1
    const int kind = pass == 0 ? 0 : (pass == 1 && in3 ? 1 : 2);
    const int rowbase = kind == 0 ? 128 : (kind == 1 ? 64 : 0);
    __syncthreads();
    for (int v = tid; v < 4096; v += 256) {
      const int i = v & 63, o = v >> 6;
      float a;
      if (kind == 0) a = w5[(size_t)(o * 64 + i) * 25 + t];
      else if (kind == 1) a = w3[(size_t)(o * 64 + i) * 9 + t3];
      else a = w1[o * 64 + i];
      At[swz(i, o)] = a;
    }
    for (int v = tid; v < 1024; v += 256) {
      const int row = v >> 4, c4 = (v & 15) * 4;
      *(float4*)&Bt[swz(row, c4)] = *(const float4*)(Wsel + (rowbase + row) * 64 + c4);
    }
    __syncthreads();
#pragma unroll
    for (int o4 = 0; o4 < 16; ++o4) {
      float4 a[4], b[4];
#pragma unroll
      for (int i = 0; i < 4; ++i) a[i] = *(const float4*)&At[swz(ty * 4 + i, o4 * 4)];
#pragma unroll
      for (int u = 0; u < 4; ++u) b[u] = *(const float4*)&Bt[swz(o4 * 4 + u, tx * 4)];
#pragma unroll
      for (int i = 0; i < 4; ++i)
#pragma unroll
        for (int j = 0; j < 4; ++j)
#pragma unroll
          for (int u = 0; u < 4; ++u)
            acc[i][j] = fmaf(fget(a[i], u), fget(b[u], j), acc[i][j]);
    }
  }
  // epilogue: scatter into B-fragment order with hi/lo split
#pragma unroll
  for (int ii = 0; ii < 4; ++ii) {
    const int i = ty * 4 + ii;
    const int s = i >> 5, lg = (i >> 3) & 3, j = i & 7;
#pragma unroll
    for (int jj = 0; jj < 4; ++jj) {
      const int em = tx * 4 + jj;
      const int q = which * 4 + (em >> 4), lr = em & 15;
      const size_t off = ((size_t)(t * 12 + q) * 2 + s) * 512 + (lg * 16 + lr) * 8 + j;
      const float val = acc[ii][jj];
      const unsigned short h = f2bf(val);
      Bfh[off] = h;
      Bfl[off] = f2bf(val - bf2f(h));
    }
  }
}

// effective bias: beff[e] = bcat[e] + sum_row bconv[row] * Wcat[row][e]
__global__ __launch_bounds__(192) void beff_kernel(
    const float* __restrict__ b1, const float* __restrict__ b3,
    const float* __restrict__ b5, const float* __restrict__ bq,
    const float* __restrict__ bk, const float* __restrict__ bv,
    const float* __restrict__ wq, const float* __restrict__ wk,
    const float* __restrict__ wv, float* __restrict__ beff) {
  const int e = threadIdx.x;
  const int em = e & 63, which = e >> 6;
  const float* Wsel = which == 0 ? wq : (which == 1 ? wk : wv);
  const float* bsel = which == 0 ? bq : (which == 1 ? bk : bv);
  float s = bsel[em];
  for (int row = 0; row < 192; ++row) {
    const float bc = row < 64 ? b1[row] : (row < 128 ? b3[row - 64] : b5[row - 128]);
    s += bc * Wsel[row * 64 + em];
  }
  beff[e] = s;
}

// ---------------- fused im2col GEMM: x -> Q(hi/lo), K(hi/lo), V ----------------
// Block: 64 pixels (8x8 spatial) x 192 outputs. 8 waves: wave = (half, pg);
// wave handles pixel-group pg (16 pixels), output quadrants half*6..half*6+5.
__global__ __launch_bounds__(512) void fused_qkv_kernel(
    const float* __restrict__ x, const unsigned short* __restrict__ Bfh,
    const unsigned short* __restrict__ Bfl, const float* __restrict__ beff,
    unsigned short* __restrict__ Qhi, unsigned short* __restrict__ Qlo,
    unsigned short* __restrict__ Khi, unsigned short* __restrict__ Klo,
    float* __restrict__ Vm) {
  __shared__ unsigned short Lh[144 * 64];
  __shared__ unsigned short Ll[144 * 64];
  const int b = blockIdx.y;
  const int sb = blockIdx.x;
  const int y0 = (sb >> 3) * 8, x0 = (sb & 7) * 8;
  const int tid = threadIdx.x;
  const int l = tid & 63, lr = l & 15, lg = l >> 4;
  const int pg = (tid >> 6) & 3, half6 = (tid >> 8) * 6;
  const float* xb = x + (size_t)b * CCH * N_PIX;
  // stage 12x12x64 patch as bf16 hi/lo, XOR-swizzled on the 8-ch granule
  for (int it = 0; it < 18; ++it) {
    const int idx = it * 512 + tid;
    const int c = idx / 144;
    const int pr = idx - c * 144;
    const int py = pr / 12, px = pr - py * 12;
    const int gy = y0 - 2 + py, gx = x0 - 2 + px;
    float v = 0.f;
    if (gy >= 0 && gy < 64 && gx >= 0 && gx < 64) v = xb[c * N_PIX + gy * 64 + gx];
    const unsigned short h = f2bf(v);
    const int a = pr * 64 + (c ^ ((pr & 7) << 3));
    Lh[a] = h;
    Ll[a] = f2bf(v - bf2f(h));
  }
  __syncthreads();
  const int p = pg * 16 + lr;  // this lane's A-row pixel
  const int prp = (p >> 3) * 12 + (p & 7);
  f32x4 acc[6];
#pragma unroll
  for (int q6 = 0; q6 < 6; ++q6) acc[q6] = (f32x4){0.f, 0.f, 0.f, 0.f};
  for (int ky = 0; ky < 5; ++ky) {
    for (int kx = 0; kx < 5; ++kx) {
      const int t = ky * 5 + kx;
      const int prt = prp + ky * 12 + kx;
      const int rb = prt * 64, sw = (prt & 7) << 3;
      const short8 ah0 = *(const short8*)&Lh[rb + ((lg << 3) ^ sw)];
      const short8 ah1 = *(const short8*)&Lh[rb + ((32 + (lg << 3)) ^ sw)];
      const short8 al0 = *(const short8*)&Ll[rb + ((lg << 3) ^ sw)];
      const short8 al1 = *(const short8*)&Ll[rb + ((32 + (lg << 3)) ^ sw)];
#pragma unroll
      for (int q6 = 0; q6 < 6; ++q6) {
        const size_t f = ((size_t)(t * 12 + half6 + q6)) * 2;
        const short8 bh0 = *(const short8*)&Bfh[f * 512 + l * 8];
        const short8 bh1 = *(const short8*)&Bfh[(f + 1) * 512 + l * 8];
        const short8 bl0 = *(const short8*)&Bfl[f * 512 + l * 8];
        const short8 bl1 = *(const short8*)&Bfl[(f + 1) * 512 + l * 8];
        acc[q6] = __builtin_amdgcn_mfma_f32_16x16x32_bf16(ah0, bh0, acc[q6], 0, 0, 0);
        acc[q6] = __builtin_amdgcn_mfma_f32_16x16x32_bf16(ah1, bh1, acc[q6], 0, 0, 0);
        acc[q6] = __builtin_amdgcn_mfma_f32_16x16x32_bf16(al0, bh0, acc[q6], 0, 0, 0);
        acc[q6] = __builtin_amdgcn_mfma_f32_16x16x32_bf16(al1, bh1, acc[q6], 0, 0, 0);
        acc[q6] = __builtin_amdgcn_mfma_f32_16x16x32_bf16(ah0, bl0, acc[q6], 0, 0, 0);
        acc[q6] = __builtin_amdgcn_mfma_f32_16x16x32_bf16(ah1, bl1, acc[q6], 0, 0, 0);
      }
    }
  }
  // epilogue: D col = l&15 -> e, row = lg*4+r -> pixel
  const size_t base = (size_t)b * N_PIX;
#pragma unroll
  for (int q6 = 0; q6 < 6; ++q6) {
    const int e = (half6 + q6) * 16 + lr;
    const int which = e >> 6, em = e & 63;
    const float be = beff[e];
#pragma unroll
    for (int r = 0; r < 4; ++r) {
      const int pp = pg * 16 + lg * 4 + r;
      const int n = (y0 + (pp >> 3)) * 64 + x0 + (pp & 7);
      const float val = acc[q6][r] + be;
      const size_t off = (base + n) * 64 + em;
      if (which == 2) {
        Vm[off] = val;
      } else {
        const unsigned short h = f2bf(val);
        const unsigned short lo = f2bf(val - bf2f(h));
        if (which == 0) {
          Qhi[off] = h;
          Qlo[off] = lo;
        } else {
          Khi[off] = h;
          Klo[off] = lo;
        }
      }
    }
  }
}

// ---------------- sweep 1: partial row sums of exp(z), MFMA split-bf16 ----------------
__global__ __launch_bounds__(256) void qk_s_kernel(
    const unsigned short* __restrict__ Qhi, const unsigned short* __restrict__ Qlo,
    const unsigned short* __restrict__ Khi, const unsigned short* __restrict__ Klo,
    float* __restrict__ s_part) {
  __shared__ float red[4][64];
  const int b = blockIdx.z, kc = blockIdx.y, q0 = blockIdx.x * 64;
  const int tid = threadIdx.x, w = tid >> 6, l = tid & 63;
  const int lr = l & 15, lg = l >> 4;
  const size_t base = (size_t)b * N_PIX;
  short8 qh[4][2], ql[4][2];
#pragma unroll
  for (int qs = 0; qs < 4; ++qs) {
    const size_t qoff = (base + q0 + qs * 16 + lr) * 64 + lg * 8;
    qh[qs][0] = *(const short8*)(Qhi + qoff);
    qh[qs][1] = *(const short8*)(Qhi + qoff + 32);
    ql[qs][0] = *(const short8*)(Qlo + qoff);
    ql[qs][1] = *(const short8*)(Qlo + qoff + 32);
  }
  float racc[4][4];
#pragma unroll
  for (int qs = 0; qs < 4; ++qs)
#pragma unroll
    for (int r = 0; r < 4; ++r) racc[qs][r] = 0.f;
  for (int kt = w; kt < 8; kt += 4) {
    const int kb = kc * 512 + kt * 64;
#pragma unroll
    for (int ct = 0; ct < 4; ++ct) {
      const size_t koff = (base + kb + ct * 16 + lr) * 64 + lg * 8;
      const short8 kh0 = *(const short8*)(Khi + koff);
      const short8 kh1 = *(const short8*)(Khi + koff + 32);
      const short8 kl0 = *(const short8*)(Klo + koff);
      const short8 kl1 = *(const short8*)(Klo + koff + 32);
#pragma unroll
      for (int qs = 0; qs < 4; ++qs) {
        f32x4 acc = {0.f, 0.f, 0.f, 0.f};
        acc = __builtin_amdgcn_mfma_f32_16x16x32_bf16(qh[qs][0], kh0, acc, 0, 0, 0);
        acc = __builtin_amdgcn_mfma_f32_16x16x32_bf16(qh[qs][1], kh1, acc, 0, 0, 0);
        acc = __builtin_amdgcn_mfma_f32_16x16x32_bf16(ql[qs][0], kh0, acc, 0, 0, 0);
        acc = __builtin_amdgcn_mfma_f32_16x16x32_bf16(ql[qs][1], kh1, acc, 0, 0, 0);
        acc = __builtin_amdgcn_mfma_f32_16x16x32_bf16(qh[qs][0], kl0, acc, 0, 0, 0);
        acc = __builtin_amdgcn_mfma_f32_16x16x32_bf16(qh[qs][1], kl1, acc, 0, 0, 0);
#pragma unroll
        for (int r = 0; r < 4; ++r) racc[qs][r] += __expf(acc[r] * 0.125f);
      }
    }
  }
#pragma unroll
  for (int qs = 0; qs < 4; ++qs)
#pragma unroll
    for (int r = 0; r < 4; ++r)
#pragma unroll
      for (int m = 1; m < 16; m <<= 1) racc[qs][r] += __shfl_xor(racc[qs][r], m);
  if (lr == 0) {
#pragma unroll
    for (int qs = 0; qs < 4; ++qs)
#pragma unroll
      for (int r = 0; r < 4; ++r) red[w][qs * 16 + lg * 4 + r] = racc[qs][r];
  }
  __syncthreads();
  if (tid < 64) {
    float s = red[0][tid] + red[1][tid] + red[2][tid] + red[3][tid];
    s_part[((size_t)(b * 8 + kc) << 12) + q0 + tid] = s;
  }
}

// ---------------- combine partial sums -> invs ----------------
__global__ __launch_bounds__(256) void combine_kernel(const float* __restrict__ s_part,
                                                      float* __restrict__ invs) {
  const int g = blockIdx.x * 256 + threadIdx.x;  // 0..16383
  const int b = g >> 12, q = g & 4095;
  float s = 0.f;
#pragma unroll
  for (int kc = 0; kc < 8; ++kc) s += s_part[((size_t)(b * 8 + kc) << 12) + q];
  invs[g] = 1.f / s;
}

// ---------------- sweep 2: column sums of normalized p, MFMA split-bf16 ----------------
__global__ __launch_bounds__(256) void colsum_kernel2(
    const unsigned short* __restrict__ Qhi, const unsigned short* __restrict__ Qlo,
    const unsigned short* __restrict__ Khi, const unsigned short* __restrict__ Klo,
    const float* __restrict__ invs, float* __restrict__ cs_part) {
  __shared__ float invs_l[512];
  __shared__ float red[4][64];
  const int b = blockIdx.z, qc = blockIdx.y, k0 = blockIdx.x * 64;
  const int tid = threadIdx.x, w = tid >> 6, l = tid & 63;
  const int lr = l & 15, lg = l >> 4;
  const size_t base = (size_t)b * N_PIX;
  for (int v = tid; v < 512; v += 256) invs_l[v] = invs[b * N_PIX + qc * 512 + v];
  short8 kh[4][2], kl[4][2];
#pragma unroll
  for (int ks = 0; ks < 4; ++ks) {
    const size_t koff = (base + k0 + ks * 16 + lr) * 64 + lg * 8;
    kh[ks][0] = *(const short8*)(Khi + koff);
    kh[ks][1] = *(const short8*)(Khi + koff + 32);
    kl[ks][0] = *(const short8*)(Klo + koff);
    kl[ks][1] = *(const short8*)(Klo + koff + 32);
  }
  float kacc[4][4];
#pragma unroll
  for (int ks = 0; ks < 4; ++ks)
#pragma unroll
    for (int r = 0; r < 4; ++r) kacc[ks][r] = 0.f;
  __syncthreads();
  for (int qt = w; qt < 8; qt += 4) {
    const int qb = qc * 512 + qt * 64;
#pragma unroll
    for (int ct = 0; ct < 4; ++ct) {
      const size_t qoff = (base + qb + ct * 16 + lr) * 64 + lg * 8;
      const short8 qh0 = *(const short8*)(Qhi + qoff);
      const short8 qh1 = *(const short8*)(Qhi + qoff + 32);
      const short8 ql0 = *(const short8*)(Qlo + qoff);
      const short8 ql1 = *(const short8*)(Qlo + qoff + 32);
      const float iv = invs_l[qt * 64 + ct * 16 + lr];
#pragma unroll
      for (int ks = 0; ks < 4; ++ks) {
        f32x4 acc = {0.f, 0.f, 0.f, 0.f};
        acc = __builtin_amdgcn_mfma_f32_16x16x32_bf16(kh[ks][0], qh0, acc, 0, 0, 0);
        acc = __builtin_amdgcn_mfma_f32_16x16x32_bf16(kh[ks][1], qh1, acc, 0, 0, 0);
        acc = __builtin_amdgcn_mfma_f32_16x16x32_bf16(kl[ks][0], qh0, acc, 0, 0, 0);
        acc = __builtin_amdgcn_mfma_f32_16x16x32_bf16(kl[ks][1], qh1, acc, 0, 0, 0);
        acc = __builtin_amdgcn_mfma_f32_16x16x32_bf16(kh[ks][0], ql0, acc, 0, 0, 0);
        acc = __builtin_amdgcn_mfma_f32_16x16x32_bf16(kh[ks][1], ql1, acc, 0, 0, 0);
#pragma unroll
        for (int r = 0; r < 4; ++r) kacc[ks][r] += __expf(acc[r] * 0.125f) * iv;
      }
    }
  }
#pragma unroll
  for (int ks = 0; ks < 4; ++ks)
#pragma unroll
    for (int r = 0; r < 4; ++r)
#pragma unroll
      for (int m = 1; m < 16; m <<= 1) kacc[ks][r] += __shfl_xor(kacc[ks][r], m);
  if (lr == 0) {
#pragma unroll
    for (int ks = 0; ks < 4; ++ks)
#pragma unroll
      for (int r = 0; r < 4; ++r) red[w][ks * 16 + lg * 4 + r] = kacc[ks][r];
  }
  __syncthreads();
  if (tid < 64) {
    float s = red[0][tid] + red[1][tid] + red[2][tid] + red[3][tid];
    cs_part[((size_t)(b * 8 + qc) << 12) + k0 + tid] = s;
  }
}

// ---------------- top-128 per batch: deterministic 4-pass radix select ----------------
// Keys: order-preserving uint map of float. Threshold T = 128th largest; select all
// keys > T plus the lowest-indexed `need` keys == T (jax.lax.top_k tie semantics).
// Slot assignment is scan-based (no atomic ordering) -> bit-deterministic output.
__global__ __launch_bounds__(256) void topk_kernel(const float* __restrict__ cs_part,
                                                   int* __restrict__ topk) {
  __shared__ unsigned keys[4096];
  __shared__ unsigned hist[256];
  __shared__ unsigned sbuf[256];
  __shared__ unsigned selB, selNeed;
  const int b = blockIdx.x, tid = threadIdx.x;
  for (int v = tid; v < 4096; v += 256) {
    float s = 0.f;
#pragma unroll
    for (int qc = 0; qc < 8; ++qc) s += cs_part[((size_t)(b * 8 + qc) << 12) + v];
    unsigned u = __float_as_uint(s);
    keys[v] = (u & 0x80000000u) ? ~u : (u | 0x80000000u);
  }
  unsigned need = 128, prefix = 0;
  __syncthreads();
  for (int d = 3; d >= 0; --d) {
    const int shift = d * 8;
    hist[tid] = 0;
    __syncthreads();
    for (int v = tid; v < 4096; v += 256) {
      const unsigned k = keys[v];
      if (d == 3 || (k >> (shift + 8)) == prefix)
        atomicAdd(&hist[(k >> shift) & 255], 1u);
    }
    __syncthreads();
    // suffix scan: sbuf[t] = sum_{b'>=t} hist[b']
    sbuf[tid] = hist[tid];
    __syncthreads();
    for (int off = 1; off < 256; off <<= 1) {
      const unsigned add = (tid + off < 256) ? sbuf[tid + off] : 0;
      __syncthreads();
      sbuf[tid] += add;
      __syncthreads();
    }
    const unsigned sufGe = sbuf[tid];
    const unsigned sufGt = (tid < 255) ? sbuf[tid + 1] : 0;
    if (sufGt < need && need <= sufGe) {
      selB = (unsigned)tid;
      selNeed = need - sufGt;
    }
    __syncthreads();
    prefix = (prefix << 8) | selB;
    need = selNeed;
    __syncthreads();
  }
  const unsigned T = prefix;
  // per-thread counts over its contiguous 16-element chunk
  unsigned gtc = 0, eqc = 0;
#pragma unroll
  for (int j = 0; j < 16; ++j) {
    const unsigned k = keys[tid * 16 + j];
    gtc += (k > T);
    eqc += (k == T);
  }
  sbuf[tid] = (gtc << 16) | eqc;
  __syncthreads();
  // inclusive prefix scan (packed)
  for (int off = 1; off < 256; off <<= 1) {
    const unsigned add = (tid >= off) ? sbuf[tid - off] : 0;
    __syncthreads();
    sbuf[tid] += add;
    __syncthreads();
  }
  const unsigned incl = sbuf[tid];
  const unsigned gBase = (incl >> 16) - gtc;
  const unsigned eBase = (incl & 0xffffu) - eqc;
  const unsigned nGt = sbuf[255] >> 16;  // total greater-than count = 128 - need
  unsigned g = 0, e = 0;
#pragma unroll
  for (int j = 0; j < 16; ++j) {
    const int idx = tid * 16 + j;
    const unsigned k = keys[idx];
    if (k > T) {
      topk[b * 128 + gBase + g] = idx;
      ++g;
    } else if (k == T) {
      if (eBase + e < need) topk[b * 128 + nGt + eBase + e] = idx;
      ++e;
    }
  }
}

// 64q x 64k z-tile: z = (Q . K^T) / 8, 4x4 per thread (fp32 path for attn_out)
__device__ __forceinline__ void qk_tile(const float* Ql, const float* Kl, int tx,
                                        int ty, float z[4][4]) {
  float acc[4][4];
#pragma unroll
  for (int i = 0; i < 4; ++i)
#pragma unroll
    for (int j = 0; j < 4; ++j) acc[i][j] = 0.f;
#pragma unroll
  for (int e4 = 0; e4 < 16; ++e4) {
    float4 qa[4], ka[4];
#pragma unroll
    for (int i = 0; i < 4; ++i) qa[i] = *(const float4*)&Ql[swz(ty * 4 + i, e4 * 4)];
#pragma unroll
    for (int j = 0; j < 4; ++j) ka[j] = *(const float4*)&Kl[swz(tx * 4 + j, e4 * 4)];
#pragma unroll
    for (int i = 0; i < 4; ++i)
#pragma unroll
      for (int j = 0; j < 4; ++j)
#pragma unroll
        for (int u = 0; u < 4; ++u)
          acc[i][j] = fmaf(fget(qa[i], u), fget(ka[j], u), acc[i][j]);
  }
#pragma unroll
  for (int i = 0; i < 4; ++i)
#pragma unroll
    for (int j = 0; j < 4; ++j) z[i][j] = acc[i][j] * 0.125f;
}

// ---------------- masked attention output: out1[q,c] = sum_{k in top} p * V ---------
__global__ __launch_bounds__(256) void attn_out_kernel(
    const unsigned short* __restrict__ Qhp, const unsigned short* __restrict__ Qlp,
    const unsigned short* __restrict__ Khp, const unsigned short* __restrict__ Klp,
    const float* __restrict__ Vm, const float* __restrict__ invs,
    const int* __restrict__ topkb, float* __restrict__ out1) {
  __shared__ float Qld[64 * 68], Kld[64 * 68], Vt[64 * 68], Pl[64 * 68];
  __shared__ int sidx[64];
  const int b = blockIdx.y, q0 = blockIdx.x * 64;
  const int tid = threadIdx.x, tx = tid & 15, ty = tid >> 4;
  const size_t base = (size_t)b * N_PIX;
  for (int v = tid; v < 1024; v += 256) {
    int row = v >> 4, c4 = (v & 15) * 4;
    size_t off = (base + q0 + row) * 64 + c4;
    ushort4 h = *(const ushort4*)(Qhp + off);
    ushort4 lo = *(const ushort4*)(Qlp + off);
    float4 f;
    f.x = bf2f(h.x) + bf2f(lo.x);
    f.y = bf2f(h.y) + bf2f(lo.y);
    f.z = bf2f(h.z) + bf2f(lo.z);
    f.w = bf2f(h.w) + bf2f(lo.w);
    *(float4*)&Qld[swz(row, c4)] = f;
  }
  float is[4];
#pragma unroll
  for (int i = 0; i < 4; ++i) is[i] = invs[base + q0 + ty * 4 + i];
  float acc[4][4];
#pragma unroll
  for (int i = 0; i < 4; ++i)
#pragma unroll
    for (int j = 0; j < 4; ++j) acc[i][j] = 0.f;
  for (int ch = 0; ch < 2; ++ch) {
    __syncthreads();
    if (tid < 64) sidx[tid] = topkb[b * 128 + ch * 64 + tid];
    __syncthreads();
    for (int v = tid; v < 1024; v += 256) {
      int row = v >> 4, c4 = (v & 15) * 4;
      size_t off = (base + sidx[row]) * 64 + c4;
      ushort4 h = *(const ushort4*)(Khp + off);
      ushort4 lo = *(const ushort4*)(Klp + off);
      float4 f;
      f.x = bf2f(h.x) + bf2f(lo.x);
      f.y = bf2f(h.y) + bf2f(lo.y);
      f.z = bf2f(h.z) + bf2f(lo.z);
      f.w = bf2f(h.w) + bf2f(lo.w);
      *(float4*)&Kld[swz(row, c4)] = f;
    }
    for (int v = tid; v < 4096; v += 256) {
      int row = v >> 6, c = v & 63;
      Vt[swz(c, row)] = Vm[(base + sidx[row]) * 64 + c];
    }
    __syncthreads();
    float z[4][4];
    qk_tile(Qld, Kld, tx, ty, z);
#pragma unroll
    for (int i = 0; i < 4; ++i)
#pragma unroll
      for (int j = 0; j < 4; ++j)
        Pl[swz(ty * 4 + i, tx * 4 + j)] = __expf(z[i][j]) * is[i];
    __syncthreads();
#pragma unroll
    for (int k4 = 0; k4 < 16; ++k4) {
      float4 pr[4], vr[4];
#pragma unroll
      for (int i = 0; i < 4; ++i) pr[i] = *(const float4*)&Pl[swz(ty * 4 + i, k4 * 4)];
#pragma unroll
      for (int j = 0; j < 4; ++j) vr[j] = *(const float4*)&Vt[swz(tx * 4 + j, k4 * 4)];
#pragma unroll
      for (int i = 0; i < 4; ++i)
#pragma unroll
        for (int j = 0; j < 4; ++j)
#pragma unroll
          for (int u = 0; u < 4; ++u)
            acc[i][j] = fmaf(fget(pr[i], u), fget(vr[j], u), acc[i][j]);
    }
  }
#pragma unroll
  for (int i = 0; i < 4; ++i) {
    float4 o;
    o.x = acc[i][0];
    o.y = acc[i][1];
    o.z = acc[i][2];
    o.w = acc[i][3];
    *(float4*)(out1 + (base + q0 + ty * 4 + i) * 64 + tx * 4) = o;
  }
}

// ---------------- final projection + transpose to [B,C,H,W] ----------------
__global__ __launch_bounds__(256) void proj_kernel(
    const float* __restrict__ out1, const float* __restrict__ wo,
    const float* __restrict__ bo, float* __restrict__ dout) {
  __shared__ float Al[64 * 68], Wl[64 * 68], Yl[64 * 68];
  const int tid = threadIdx.x, tx = tid & 15, ty = tid >> 4;
  const size_t r0 = (size_t)blockIdx.x * 64;
  const int b = (int)(r0 >> 12);
  const int n0 = (int)(r0 & 4095);
  for (int v = tid; v < 1024; v += 256) {
    int row = v >> 4, c4 = (v & 15) * 4;
    *(float4*)&Al[swz(row, c4)] = *(const float4*)(out1 + (r0 + row) * 64 + c4);
    *(float4*)&Wl[swz(row, c4)] = *(const float4*)(wo + row * 64 + c4);
  }
  __syncthreads();
  float acc[4][4];
#pragma unroll
  for (int i = 0; i < 4; ++i)
#pragma unroll
    for (int j = 0; j < 4; ++j) acc[i][j] = 0.f;
#pragma unroll
  for (int e4 = 0; e4 < 16; ++e4) {
    float4 a[4], wr[4];
#pragma unroll
    for (int i = 0; i < 4; ++i) a[i] = *(const float4*)&Al[swz(ty * 4 + i, e4 * 4)];
#pragma unroll
    for (int u = 0; u < 4; ++u) wr[u] = *(const float4*)&Wl[swz(e4 * 4 + u, tx * 4)];
#pragma unroll
    for (int i = 0; i < 4; ++i)
#pragma unroll
      for (int j = 0; j < 4; ++j)
#pragma unroll
        for (int u = 0; u < 4; ++u)
          acc[i][j] = fmaf(fget(a[i], u), fget(wr[u], j), acc[i][j]);
  }
#pragma unroll
  for (int i = 0; i < 4; ++i)
#pragma unroll
    for (int j = 0; j < 4; ++j)
      Yl[swz(ty * 4 + i, tx * 4 + j)] = acc[i][j] + bo[tx * 4 + j];
  __syncthreads();
  for (int v = tid; v < 4096; v += 256) {
    int c = v >> 6, nl = v & 63;
    dout[((size_t)b * 64 + c) * 4096 + n0 + nl] = Yl[swz(nl, c)];
  }
}

extern "C" void kernel_launch(void* const* d_in, const int* in_sizes, int n_in,
                              void* d_out, int out_size, void* d_ws, size_t ws_size,
                              hipStream_t stream) {
  const float* x = (const float*)d_in[0];
  const float* w1 = (const float*)d_in[1];
  const float* b1 = (const float*)d_in[2];
  const float* w3 = (const float*)d_in[3];
  const float* b3 = (const float*)d_in[4];
  const float* w5 = (const float*)d_in[5];
  const float* b5 = (const float*)d_in[6];
  const float* wq = (const float*)d_in[7];
  const float* bq = (const float*)d_in[8];
  const float* wk = (const float*)d_in[9];
  const float* bk = (const float*)d_in[10];
  const float* wv = (const float*)d_in[11];
  const float* bv = (const float*)d_in[12];
  const float* wo = (const float*)d_in[13];
  const float* bo = (const float*)d_in[14];

  const size_t BN = (size_t)4 * N_PIX;  // 16384
  char* p = (char*)d_ws;
  auto carve = [&](size_t bytes) -> void* {
    void* r = (void*)p;
    p += (bytes + 255) & ~(size_t)255;
    return r;
  };
  unsigned short* Bfh = (unsigned short*)carve((size_t)25 * 12 * 2 * 512 * 2);
  unsigned short* Bfl = (unsigned short*)carve((size_t)25 * 12 * 2 * 512 * 2);
  float* beff = (float*)carve(192 * 4);
  float* Vm = (float*)carve(BN * 64 * 4);
  unsigned short* Qhi = (unsigned short*)carve(BN * 64 * 2);
  unsigned short* Qlo = (unsigned short*)carve(BN * 64 * 2);
  unsigned short* Khi = (unsigned short*)carve(BN * 64 * 2);
  unsigned short* Klo = (unsigned short*)carve(BN * 64 * 2);
  float* s_part = (float*)carve((size_t)4 * 8 * 4096 * 4);
  float* invs = (float*)carve(BN * 4);
  float* cs_part = (float*)carve((size_t)4 * 8 * 4096 * 4);
  int* topkbuf = (int*)carve(512 * 4);
  float* out1 = (float*)carve(BN * 64 * 4);

  prep_kernel<<<dim3(3, 25), 256, 0, stream>>>(w1, w3, w5, wq, wk, wv, Bfh, Bfl);
  beff_kernel<<<1, 192, 0, stream>>>(b1, b3, b5, bq, bk, bv, wq, wk, wv, beff);
  fused_qkv_kernel<<<dim3(64, 4), 512, 0, stream>>>(x, Bfh, Bfl, beff, Qhi, Qlo, Khi,
                                                    Klo, Vm);
  qk_s_kernel<<<dim3(64, 8, 4), 256, 0, stream>>>(Qhi, Qlo, Khi, Klo, s_part);
  combine_kernel<<<64, 256, 0, stream>>>(s_part, invs);
  colsum_kernel2<<<dim3(64, 8, 4), 256, 0, stream>>>(Qhi, Qlo, Khi, Klo, invs, cs_part);
  topk_kernel<<<4, 256, 0, stream>>>(cs_part, topkbuf);
  attn_out_kernel<<<dim3(64, 4), 256, 0, stream>>>(Qhi, Qlo, Khi, Klo, Vm, invs,
                                                   topkbuf, out1);
  proj_kernel<<<256, 256, 0, stream>>>(out1, wo, bo, (float*)d_out);
}